// Round 14
// baseline (468.188 us; speedup 1.0000x reference)
//
#include <hip/hip_runtime.h>

// GATRNN: T=12 steps of {GAT1(inputs_t) -> GRU -> GAT2}, then Linear(H->D).
// All I/O fp32. Graph hardcoded: edge k: sender=k/63, receiver=k%63; node 63 inactive.
// eluf uses expm1f. final_k launched UNCONDITIONALLY (rounds 9-12 launcher bug).
// Round 14: gru_fc5 -> gru_fc7 (gi loads hoisted to kernel entry). Single change
// vs round 13 for clean A/B; fc7 was exonerated of the round-10/11 failures
// (those were the final_k launcher bug).

#define T_   12
#define B_   32
#define N_   64
#define D_   2
#define H_   128
#define HID_ 32
#define HEAD_ 4
#define NA_  63

__device__ __forceinline__ float eluf(float x){ return x>0.f ? x : expm1f(x); }

// ---- ws layout (floats) ----
#define OFF_H    0u
#define OFF_X1   262144u          // T*B*N*HID (dead after big att -> WTb)
#define OFF_PS1  1048576u        // dead after big att -> x2 odd buffer
#define OFF_PR1  1146880u        // dead after big att -> ps/pr odd buffers
#define OFF_XG   1245184u         // T*B*N*H
#define OFF_X2   4390912u
#define OFF_PS2  4456448u
#define OFF_PR2  4464640u         // end 4472832
#define OFF_WT   OFF_X1           // 768*128 floats
#define OFF_GI   4472832u         // T*B*N*384 = 9437184 floats (path A only)
#define WS_NEED_A ((4472832ull + 9437184ull) * 4ull)

// GAT1 fc1 + edge projections for ALL t, grid = T*B, block 256.
__global__ void gat1_fc(const float* __restrict__ inp, const float* __restrict__ W1,
                        const float* __restrict__ b1, const float* __restrict__ W2,
                        const float* __restrict__ b2,
                        float* __restrict__ x1_all, float* __restrict__ ps_all,
                        float* __restrict__ pr_all){
  int grp = blockIdx.x;
  int tid = threadIdx.x;
  __shared__ float sx1[N_*HID_];
  __shared__ float sW1[HID_*D_];
  __shared__ float sb1[HID_];
  __shared__ float sW2[HEAD_*2*HID_];
  __shared__ float sxin[N_*D_];
  if(tid < 64)  sW1[tid] = W1[tid];
  if(tid < 32)  sb1[tid] = b1[tid];
  sW2[tid] = W2[tid];
  if(tid < 128) sxin[tid] = inp[grp*N_*D_ + tid];
  __syncthreads();
  for(int o = tid; o < N_*HID_; o += 256){
    int n = o >> 5, k = o & 31;
    float v = sb1[k] + sxin[n*2]*sW1[k*2] + sxin[n*2+1]*sW1[k*2+1];
    sx1[o] = v;
    x1_all[grp*N_*HID_ + o] = v;
  }
  __syncthreads();
  for(int p = tid; p < N_*8; p += 256){
    int n = p >> 3, q = p & 7, hh = q & 3;
    const float* w  = sW2 + hh*64 + ((q < 4) ? 0 : 32);
    const float* xr = sx1 + n*32;
    float acc = (q < 4) ? b2[hh] : 0.f;
    #pragma unroll
    for(int c = 0; c < 32; c++) acc += xr[c]*w[c];
    if(q < 4) ps_all[grp*N_*HEAD_ + n*4 + hh] = acc;
    else      pr_all[grp*N_*HEAD_ + n*4 + hh] = acc;
  }
}

// Blocked-transposed GRU weights: WTb[k4][j][kk]; j<384 Wih, j>=384 Whh.
__global__ void prep_wt(const float* __restrict__ Wih, const float* __restrict__ Whh,
                        float* __restrict__ wtb){
  int idx = blockIdx.x*256 + threadIdx.x;
  int k4 = idx / 768, j = idx - k4*768;
  const float* src = (j < 384) ? (Wih + (size_t)j*H_) : (Whh + (size_t)(j-384)*H_);
  ((float4*)wtb)[idx] = ((const float4*)src)[k4];
}

// Big attention (all T). grid = 2*T*B (g, d-half), block 256.
__global__ __launch_bounds__(256) void gat_att_big2(const float* __restrict__ x1,
    const float* __restrict__ ps, const float* __restrict__ pr,
    float* __restrict__ out){
  int blk = blockIdx.x, g = blk >> 1, dh = blk & 1, tid = threadIdx.x;
  __shared__ float sX[N_*HID_];
  __shared__ float sPs[N_*HEAD_];
  __shared__ float sPr[N_*HEAD_];
  {
    const float4* xs = (const float4*)(x1 + (size_t)g*(N_*HID_));
    ((float4*)sX)[tid]       = xs[tid];
    ((float4*)sX)[tid + 256] = xs[tid + 256];
    sPs[tid] = ps[g*(N_*HEAD_) + tid];
    sPr[tid] = pr[g*(N_*HEAD_) + tid];
  }
  __syncthreads();
  float* outg = out + (size_t)g*(N_*H_);
  if(tid < NA_*HEAD_){
    int r = tid, hh = r & 3;
    float prv = sPr[r];
    float tmax = -1e30f;
    for(int i = 0; i < NA_; i++) tmax = fmaxf(tmax, sPs[i*4 + hh]);
    float m = eluf(tmax + prv);
    float4 acc[4];
    #pragma unroll
    for(int k = 0; k < 4; k++) acc[k] = make_float4(0.f,0.f,0.f,0.f);
    float s = 0.f;
    #pragma unroll 3
    for(int i = 0; i < NA_; i++){
      float tt = sPs[i*4 + hh] + prv;
      float v = tt > 0.f ? tt : expm1f(tt);
      float p = expf(v - m);
      s += p;
      const float4* sxp = (const float4*)&sX[i*32 + dh*16];
      #pragma unroll
      for(int k = 0; k < 4; k++){
        float4 xv = sxp[k];
        acc[k].x += p*xv.x; acc[k].y += p*xv.y;
        acc[k].z += p*xv.z; acc[k].w += p*xv.w;
      }
    }
    float inv = 1.f/s;
    float4* orow = (float4*)(outg + (r>>2)*H_ + hh*32 + dh*16);
    #pragma unroll
    for(int k = 0; k < 4; k++){
      float4 o;
      o.x = eluf(acc[k].x*inv); o.y = eluf(acc[k].y*inv);
      o.z = eluf(acc[k].z*inv); o.w = eluf(acc[k].w*inv);
      orow[k] = o;
    }
  } else {
    // tid 252..255 -> head hh: zero row 63's [hh*32 + dh*16, +16) slice
    int hh = tid - NA_*HEAD_;
    float4 z4 = make_float4(0.f,0.f,0.f,0.f);
    float4* zp = (float4*)(outg + NA_*H_ + hh*32 + dh*16);
    zp[0]=z4; zp[1]=z4; zp[2]=z4; zp[3]=z4;
  }
}

// gi = xg @ Wih^T. Thread owns 3 gate-cols x 8 rows; block 256, grid 1536.
__global__ __launch_bounds__(256) void gi_gemm4(const float* __restrict__ xg,
    const float* __restrict__ wtb, float* __restrict__ gi){
  int tid = threadIdx.x;
  int r0 = blockIdx.x * 16;
  __shared__ __align__(16) float sxg[16][H_];
  ((float4*)sxg)[tid]       = ((const float4*)(xg + (size_t)r0*H_))[tid];
  ((float4*)sxg)[tid + 256] = ((const float4*)(xg + (size_t)r0*H_))[tid + 256];
  __syncthreads();
  int c = tid & 127, rh = (tid >> 7) * 8;
  const float4* wt4 = (const float4*)wtb;
  float ar[8]={0,0,0,0,0,0,0,0}, az[8]={0,0,0,0,0,0,0,0}, an[8]={0,0,0,0,0,0,0,0};
  #pragma unroll 2
  for(int k4 = 0; k4 < 32; k4++){
    float4 w0 = wt4[k4*768 + c];
    float4 w1 = wt4[k4*768 + 128 + c];
    float4 w2 = wt4[k4*768 + 256 + c];
    #pragma unroll
    for(int rr = 0; rr < 8; rr++){
      float4 xv = ((const float4*)sxg[rh + rr])[k4];
      ar[rr] += w0.x*xv.x + w0.y*xv.y + w0.z*xv.z + w0.w*xv.w;
      az[rr] += w1.x*xv.x + w1.y*xv.y + w1.z*xv.z + w1.w*xv.w;
      an[rr] += w2.x*xv.x + w2.y*xv.y + w2.z*xv.z + w2.w*xv.w;
    }
  }
  #pragma unroll
  for(int rr = 0; rr < 8; rr++){
    size_t base = (size_t)(r0 + rh + rr)*384;
    gi[base + c]       = ar[rr];
    gi[base + 128 + c] = az[rr];
    gi[base + 256 + c] = an[rr];
  }
}

// Fused loop kernel v3: gi loads hoisted to kernel entry (issue-early /
// consume-late; latency hides under phase-0 staging + phase-1 att).
// grid 256 x 512, 8 rows/block, k-split GRU (Whh read once/block via spart).
__global__ __launch_bounds__(512) void gru_fc7(
    const float* __restrict__ gi, const float* __restrict__ hidden0, int t0,
    const float* __restrict__ x2prev, const float* __restrict__ psprev,
    const float* __restrict__ prprev,
    const float* __restrict__ wtb,
    const float* __restrict__ bih, const float* __restrict__ bhh,
    const float* __restrict__ W1, const float* __restrict__ b1,
    const float* __restrict__ W2, const float* __restrict__ b2,
    float* __restrict__ x2, float* __restrict__ ps2, float* __restrict__ pr2){
  int tid = threadIdx.x, blk = blockIdx.x;
  int g0 = blk*8, g = blk>>3, jbase = (blk&7)*8;
  __shared__ __align__(16) float sX[N_*HID_];
  __shared__ float sPs[N_*HEAD_];
  __shared__ __align__(16) float sh[8][H_];
  __shared__ __align__(16) float shn[8][H_];
  __shared__ float spart[4][24][H_];
  __shared__ float sx2[8][HID_];

  int c = tid & 127, rg = tid >> 7, r0 = rg*2;
  // ---- gi prefetch: 6 scalar loads from L3-resident buffer, issued FIRST ----
  const float* gir0 = gi + (size_t)(g0+r0)*384;
  const float* gir1 = gi + (size_t)(g0+r0+1)*384;
  float gi_r0 = gir0[c], gi_z0 = gir0[c+128], gi_n0 = gir0[c+256];
  float gi_r1 = gir1[c], gi_z1 = gir1[c+128], gi_n1 = gir1[c+256];

  // ---- phase 0: stage ----
  if(t0){
    if(tid < 256) ((float4*)sh)[tid] = ((const float4*)(hidden0 + (size_t)g0*H_))[tid];
  } else {
    ((float4*)sX)[tid] = ((const float4*)(x2prev + (size_t)g*(N_*HID_)))[tid];
    if(tid < 256) sPs[tid] = psprev[g*(N_*HEAD_) + tid];
  }
  __syncthreads();

  // ---- phase 1: att for this block's 8 receiver rows ----
  if(!t0){
    int rl = tid >> 4, l16 = tid & 15;
    int hh = rl & 3, jrow = rl >> 2;
    int jl = jbase + jrow;
    float prv = prprev[g*(N_*HEAD_) + jbase*4 + rl];
    float tmax = -1e30f;
    for(int i = 0; i < NA_; i++) tmax = fmaxf(tmax, sPs[i*4 + hh]);
    float m = eluf(tmax + prv);
    float a0 = 0.f, a1 = 0.f, s = 0.f;
    #pragma unroll 3
    for(int i = 0; i < NA_; i++){
      float tt = sPs[i*4 + hh] + prv;
      float v = tt > 0.f ? tt : expm1f(tt);
      float p = expf(v - m);
      s += p;
      const float2 xv = *(const float2*)&sX[i*32 + l16*2];
      a0 += p*xv.x; a1 += p*xv.y;
    }
    float inv = 1.f/s;
    float h0 = (jl == NA_) ? 0.f : eluf(a0*inv);
    float h1 = (jl == NA_) ? 0.f : eluf(a1*inv);
    sh[jrow][hh*32 + l16*2]     = h0;
    sh[jrow][hh*32 + l16*2 + 1] = h1;
  }
  __syncthreads();

  // ---- phase 2: GRU partial dots (k-split) ----
  {
    const float4* wt4 = (const float4*)wtb;
    float ar[8] = {0,0,0,0,0,0,0,0};
    float az[8] = {0,0,0,0,0,0,0,0};
    float an[8] = {0,0,0,0,0,0,0,0};
    #pragma unroll
    for(int kk = 0; kk < 8; kk++){
      int k4 = rg*8 + kk;
      const float4* wk = wt4 + (size_t)k4*768 + 384 + c;   // Whh half
      float4 wr_ = wk[0], wz_ = wk[128], wn_ = wk[256];
      #pragma unroll
      for(int r = 0; r < 8; r++){
        float4 hv = ((const float4*)sh[r])[k4];
        ar[r] += wr_.x*hv.x + wr_.y*hv.y + wr_.z*hv.z + wr_.w*hv.w;
        az[r] += wz_.x*hv.x + wz_.y*hv.y + wz_.z*hv.z + wz_.w*hv.w;
        an[r] += wn_.x*hv.x + wn_.y*hv.y + wn_.z*hv.z + wn_.w*hv.w;
      }
    }
    #pragma unroll
    for(int r = 0; r < 8; r++){
      spart[rg][r][c]      = ar[r];
      spart[rg][8 + r][c]  = az[r];
      spart[rg][16 + r][c] = an[r];
    }
  }
  __syncthreads();

  // ---- phase 3: combine + GRU nonlinearity (2 rows/thread, gi from regs) ----
  {
    float bi_r = bih[c], bi_z = bih[c+H_], bi_n = bih[c+2*H_];
    float bh_r = bhh[c], bh_z = bhh[c+H_], bh_n = bhh[c+2*H_];
    #pragma unroll
    for(int rr = 0; rr < 2; rr++){
      int r = r0 + rr;
      float hr = spart[0][r][c] + spart[1][r][c] + spart[2][r][c] + spart[3][r][c] + bh_r;
      float hz = spart[0][8+r][c] + spart[1][8+r][c] + spart[2][8+r][c] + spart[3][8+r][c] + bh_z;
      float hn = spart[0][16+r][c] + spart[1][16+r][c] + spart[2][16+r][c] + spart[3][16+r][c] + bh_n;
      float ir  = (rr ? gi_r1 : gi_r0) + bi_r;
      float iz  = (rr ? gi_z1 : gi_z0) + bi_z;
      float in_ = (rr ? gi_n1 : gi_n0) + bi_n;
      float rgt = 1.f/(1.f+expf(-(ir+hr)));
      float zgt = 1.f/(1.f+expf(-(iz+hz)));
      float ngt = tanhf(in_ + rgt*hn);
      shn[r][c] = (1.f-zgt)*ngt + zgt*sh[r][c];
    }
  }
  __syncthreads();

  // ---- phase 4: GAT2 fc1 ----
  if(tid < 256){
    int r = tid >> 5, jc = tid & 31;
    const float4* wrow = (const float4*)(W1 + (size_t)jc*H_);
    const float4* hnr = (const float4*)shn[r];
    float acc = b1[jc];
    #pragma unroll 8
    for(int k4 = 0; k4 < 32; k4++){
      float4 w = wrow[k4], hv = hnr[k4];
      acc += w.x*hv.x + w.y*hv.y + w.z*hv.z + w.w*hv.w;
    }
    sx2[r][jc] = acc;
    x2[(size_t)(g0+r)*HID_ + jc] = acc;
  }
  __syncthreads();
  // ---- phase 5: GAT2 fc2 edge projections ----
  if(tid < 64){
    int r = tid >> 3, q = tid & 7, hh = q & 3;
    int base = (q < 4) ? 0 : 32;
    float acc = (q < 4) ? b2[hh] : 0.f;
    #pragma unroll
    for(int cc = 0; cc < 32; cc++) acc += sx2[r][cc]*W2[hh*64 + base + cc];
    if(q < 4) ps2[(g0+r)*HEAD_ + hh] = acc;
    else      pr2[(g0+r)*HEAD_ + hh] = acc;
  }
}

// Fallback loop GRU (round-3 proven; used only if ws too small for gi).
__global__ __launch_bounds__(512) void gru_fc3(
    const float* __restrict__ xg, const float* __restrict__ h,
    const float* __restrict__ wtb,
    const float* __restrict__ bih, const float* __restrict__ bhh,
    const float* __restrict__ W1, const float* __restrict__ b1,
    const float* __restrict__ W2, const float* __restrict__ b2,
    float* __restrict__ x2, float* __restrict__ ps2, float* __restrict__ pr2){
  int tid = threadIdx.x;
  int g0 = blockIdx.x * 8;
  __shared__ __align__(16) float sx[8][H_];
  __shared__ __align__(16) float sh[8][H_];
  __shared__ __align__(16) float shn[8][H_];
  __shared__ float sx2[8][HID_];
  if(tid < 256) ((float4*)sx)[tid]     = ((const float4*)(xg + (size_t)g0*H_))[tid];
  else          ((float4*)sh)[tid-256] = ((const float4*)(h  + (size_t)g0*H_))[tid-256];
  __syncthreads();
  int c = tid & 127, rg = tid >> 7, r0 = rg*2;
  const float4* wt4 = (const float4*)wtb;
  const float4* xr0 = (const float4*)sx[r0];
  const float4* xr1 = (const float4*)sx[r0+1];
  const float4* hp0 = (const float4*)sh[r0];
  const float4* hp1 = (const float4*)sh[r0+1];
  float air[2]={0,0}, aiz[2]={0,0}, ain[2]={0,0};
  float ahr[2]={0,0}, ahz[2]={0,0}, ahn[2]={0,0};
  #pragma unroll 2
  for(int k4 = 0; k4 < 32; k4++){
    const float4* wk = wt4 + k4*768 + c;
    float4 w0 = wk[0],   w1 = wk[128], w2 = wk[256];
    float4 w3 = wk[384], w4 = wk[512], w5 = wk[640];
    float4 xv0 = xr0[k4], xv1 = xr1[k4];
    float4 hv0 = hp0[k4], hv1 = hp1[k4];
    air[0] += w0.x*xv0.x + w0.y*xv0.y + w0.z*xv0.z + w0.w*xv0.w;
    aiz[0] += w1.x*xv0.x + w1.y*xv0.y + w1.z*xv0.z + w1.w*xv0.w;
    ain[0] += w2.x*xv0.x + w2.y*xv0.y + w2.z*xv0.z + w2.w*xv0.w;
    ahr[0] += w3.x*hv0.x + w3.y*hv0.y + w3.z*hv0.z + w3.w*hv0.w;
    ahz[0] += w4.x*hv0.x + w4.y*hv0.y + w4.z*hv0.z + w4.w*hv0.w;
    ahn[0] += w5.x*hv0.x + w5.y*hv0.y + w5.z*hv0.z + w5.w*hv0.w;
    air[1] += w0.x*xv1.x + w0.y*xv1.y + w0.z*xv1.z + w0.w*xv1.w;
    aiz[1] += w1.x*xv1.x + w1.y*xv1.y + w1.z*xv1.z + w1.w*xv1.w;
    ain[1] += w2.x*xv1.x + w2.y*xv1.y + w2.z*xv1.z + w2.w*xv1.w;
    ahr[1] += w3.x*hv1.x + w3.y*hv1.y + w3.z*hv1.z + w3.w*hv1.w;
    ahz[1] += w4.x*hv1.x + w4.y*hv1.y + w4.z*hv1.z + w4.w*hv1.w;
    ahn[1] += w5.x*hv1.x + w5.y*hv1.y + w5.z*hv1.z + w5.w*hv1.w;
  }
  float bi_r = bih[c], bi_z = bih[c+H_], bi_n = bih[c+2*H_];
  float bh_r = bhh[c], bh_z = bhh[c+H_], bh_n = bhh[c+2*H_];
  #pragma unroll
  for(int rr = 0; rr < 2; rr++){
    float ir  = air[rr]+bi_r, iz = aiz[rr]+bi_z, in_ = ain[rr]+bi_n;
    float hr  = ahr[rr]+bh_r, hz = ahz[rr]+bh_z, hn  = ahn[rr]+bh_n;
    float rgt = 1.f/(1.f+expf(-(ir+hr)));
    float zgt = 1.f/(1.f+expf(-(iz+hz)));
    float ngt = tanhf(in_ + rgt*hn);
    shn[r0+rr][c] = (1.f-zgt)*ngt + zgt*sh[r0+rr][c];
  }
  __syncthreads();
  if(tid < 256){
    int r = tid >> 5, jc = tid & 31;
    const float4* wrow = (const float4*)(W1 + (size_t)jc*H_);
    const float4* hnr = (const float4*)shn[r];
    float acc = b1[jc];
    #pragma unroll 8
    for(int k4 = 0; k4 < 32; k4++){
      float4 w = wrow[k4], hv = hnr[k4];
      acc += w.x*hv.x + w.y*hv.y + w.z*hv.z + w.w*hv.w;
    }
    sx2[r][jc] = acc;
    x2[(size_t)(g0+r)*HID_ + jc] = acc;
  }
  __syncthreads();
  if(tid < 64){
    int r = tid >> 3, q = tid & 7, hh = q & 3;
    int base = (q < 4) ? 0 : 32;
    float acc = (q < 4) ? b2[hh] : 0.f;
    #pragma unroll
    for(int cc = 0; cc < 32; cc++) acc += sx2[r][cc]*W2[hh*64 + base + cc];
    if(q < 4) ps2[(g0+r)*HEAD_ + hh] = acc;
    else      pr2[(g0+r)*HEAD_ + hh] = acc;
  }
}

// Loop/final attention. grid = B*8, block 128. (rh = r-half, dq = d-quarter).
__global__ __launch_bounds__(128) void gat_att_sm(const float* __restrict__ x1,
    const float* __restrict__ ps, const float* __restrict__ pr,
    float* __restrict__ out){
  int bid = blockIdx.x;
  int g = bid >> 3, sub = bid & 7, rh = sub >> 2, dq = sub & 3;
  int tid = threadIdx.x;
  __shared__ float sX[N_*HID_];
  __shared__ float sPs[N_*HEAD_];
  __shared__ float sPr[N_*HEAD_];
  {
    const float4* xs = (const float4*)(x1 + (size_t)g*(N_*HID_));
    #pragma unroll
    for(int k = 0; k < 4; k++) ((float4*)sX)[tid + 128*k] = xs[tid + 128*k];
    sPs[tid]       = ps[g*(N_*HEAD_) + tid];
    sPs[tid + 128] = ps[g*(N_*HEAD_) + tid + 128];
    sPr[tid]       = pr[g*(N_*HEAD_) + tid];
    sPr[tid + 128] = pr[g*(N_*HEAD_) + tid + 128];
  }
  __syncthreads();
  float* outg = out + (size_t)g*(N_*H_);
  if(tid < 126){
    int r = rh*126 + tid;
    int hh = r & 3, j = r >> 2;
    float prv = sPr[r];
    float tmax = -1e30f;
    for(int i = 0; i < NA_; i++) tmax = fmaxf(tmax, sPs[i*4 + hh]);
    float m = eluf(tmax + prv);
    float4 a0 = make_float4(0.f,0.f,0.f,0.f), a1 = a0;
    float s = 0.f;
    #pragma unroll 3
    for(int i = 0; i < NA_; i++){
      float tt = sPs[i*4 + hh] + prv;
      float v = tt > 0.f ? tt : expm1f(tt);
      float p = expf(v - m);
      s += p;
      const float4* sxp = (const float4*)&sX[i*32 + dq*8];
      float4 x0 = sxp[0], x1v = sxp[1];
      a0.x += p*x0.x;  a0.y += p*x0.y;  a0.z += p*x0.z;  a0.w += p*x0.w;
      a1.x += p*x1v.x; a1.y += p*x1v.y; a1.z += p*x1v.z; a1.w += p*x1v.w;
    }
    float inv = 1.f/s;
    float4* orow = (float4*)(outg + (size_t)j*H_ + hh*32 + dq*8);
    float4 o0, o1;
    o0.x = eluf(a0.x*inv); o0.y = eluf(a0.y*inv);
    o0.z = eluf(a0.z*inv); o0.w = eluf(a0.w*inv);
    o1.x = eluf(a1.x*inv); o1.y = eluf(a1.y*inv);
    o1.z = eluf(a1.z*inv); o1.w = eluf(a1.w*inv);
    orow[0] = o0; orow[1] = o1;
  } else if(rh == 1){
    float4 z4 = make_float4(0.f,0.f,0.f,0.f);
    float4* zrow = (float4*)(outg + NA_*H_);
    int base = dq*8 + (tid-126)*4;
    #pragma unroll
    for(int k = 0; k < 4; k++) zrow[base + k] = z4;
  }
}

// pred = h @ out_W.T + out_b. grid B, block 128.
__global__ void final_k(const float* __restrict__ h, const float* __restrict__ oW,
                        const float* __restrict__ ob, float* __restrict__ out){
  int b = blockIdx.x, tid = threadIdx.x;
  int n = tid >> 1, d = tid & 1;
  const float* hr = h + (size_t)(b*N_ + n)*H_;
  float acc = ob[d];
  #pragma unroll 8
  for(int k = 0; k < H_; k++) acc += hr[k]*oW[d*H_ + k];
  out[(b*N_ + n)*D_ + d] = acc;
}

extern "C" void kernel_launch(void* const* d_in, const int* in_sizes, int n_in,
                              void* d_out, int out_size, void* d_ws, size_t ws_size,
                              hipStream_t stream){
  const float* inputs = (const float*)d_in[0];
  const float* hidden = (const float*)d_in[1];
  const float* rn1_W1 = (const float*)d_in[4];
  const float* rn1_b1 = (const float*)d_in[5];
  const float* rn1_W2 = (const float*)d_in[6];
  const float* rn1_b2 = (const float*)d_in[7];
  const float* rn2_W1 = (const float*)d_in[8];
  const float* rn2_b1 = (const float*)d_in[9];
  const float* rn2_W2 = (const float*)d_in[10];
  const float* rn2_b2 = (const float*)d_in[11];
  const float* gWih   = (const float*)d_in[12];
  const float* gWhh   = (const float*)d_in[13];
  const float* gbih   = (const float*)d_in[14];
  const float* gbhh   = (const float*)d_in[15];
  const float* oW     = (const float*)d_in[16];
  const float* ob     = (const float*)d_in[17];
  float* ws = (float*)d_ws;

  const int use_gi = (ws_size >= WS_NEED_A) ? 1 : 0;

  gat1_fc<<<T_*B_, 256, 0, stream>>>(inputs, rn1_W1, rn1_b1, rn1_W2, rn1_b2,
                                     ws + OFF_X1, ws + OFF_PS1, ws + OFF_PR1);
  gat_att_big2<<<T_*B_*2, 256, 0, stream>>>(ws + OFF_X1, ws + OFF_PS1, ws + OFF_PR1,
                                            ws + OFF_XG);
  prep_wt<<<96, 256, 0, stream>>>(gWih, gWhh, ws + OFF_WT);

  const float* xg0  = ws + OFF_XG;
  const float* wtbp = ws + OFF_WT;
  float* hb  = ws + OFF_H;

  if(use_gi){
    gi_gemm4<<<T_*B_*N_/16, 256, 0, stream>>>(xg0, wtbp, ws + OFF_GI);
    // double-buffered x2/ps/pr (odd set reuses dead PS1/PR1 regions)
    float* x2b[2] = {ws + OFF_X2,  ws + OFF_PS1};
    float* psb[2] = {ws + OFF_PS2, ws + OFF_PR1};
    float* prb[2] = {ws + OFF_PR2, ws + OFF_PR1 + 8192};
    for(int t = 0; t < T_; t++){
      int w = t & 1, rp = w ^ 1;
      gru_fc7<<<256, 512, 0, stream>>>(ws + OFF_GI + (size_t)t*B_*N_*384,
                                       hidden, (t == 0) ? 1 : 0,
                                       x2b[rp], psb[rp], prb[rp],
                                       wtbp, gbih, gbhh,
                                       rn2_W1, rn2_b1, rn2_W2, rn2_b2,
                                       x2b[w], psb[w], prb[w]);
    }
    // T_-1 = 11 is odd -> final buffers are set 1
    gat_att_sm<<<B_*8, 128, 0, stream>>>(x2b[1], psb[1], prb[1], hb);
  } else {
    float* x2p = ws + OFF_X2;
    float* psp = ws + OFF_PS2;
    float* prp = ws + OFF_PR2;
    for(int t = 0; t < T_; t++){
      const float* hsrc = (t == 0) ? hidden : hb;
      gru_fc3<<<B_*N_/8, 512, 0, stream>>>(xg0 + (size_t)t*B_*N_*H_, hsrc,
                                           wtbp, gbih, gbhh,
                                           rn2_W1, rn2_b1, rn2_W2, rn2_b2,
                                           x2p, psp, prp);
      gat_att_sm<<<B_*8, 128, 0, stream>>>(x2p, psp, prp, hb);
    }
  }
  // UNCONDITIONAL (rounds 9-12 had this inside the else-branch — the bug).
  final_k<<<B_, 128, 0, stream>>>(hb, oW, ob, (float*)d_out);
}

// Round 15
// 459.584 us; speedup vs baseline: 1.0187x; 1.0187x over previous
//
#include <hip/hip_runtime.h>

// GATRNN: T=12 steps of {GAT1(inputs_t) -> GRU -> GAT2}, then Linear(H->D).
// All I/O fp32. Graph hardcoded: edge k: sender=k/63, receiver=k%63; node 63 inactive.
// eluf uses expm1f. final_k launched UNCONDITIONALLY (rounds 9-12 launcher bug).
// Round 15: loop kernel restructured 8rows/512thr/grid256 -> 4rows/256thr/grid512
// (2 blocks/CU so barrier stalls of one block hide under the other; LDS 66->26KB).
// gi-prefetch and w-preload both proven null (rounds 8/14) and omitted.

#define T_   12
#define B_   32
#define N_   64
#define D_   2
#define H_   128
#define HID_ 32
#define HEAD_ 4
#define NA_  63

__device__ __forceinline__ float eluf(float x){ return x>0.f ? x : expm1f(x); }

// ---- ws layout (floats) ----
#define OFF_H    0u
#define OFF_X1   262144u          // T*B*N*HID (dead after big att -> WTb)
#define OFF_PS1  1048576u        // dead after big att -> x2 odd buffer
#define OFF_PR1  1146880u        // dead after big att -> ps/pr odd buffers
#define OFF_XG   1245184u         // T*B*N*H
#define OFF_X2   4390912u
#define OFF_PS2  4456448u
#define OFF_PR2  4464640u         // end 4472832
#define OFF_WT   OFF_X1           // 768*128 floats
#define OFF_GI   4472832u         // T*B*N*384 = 9437184 floats (path A only)
#define WS_NEED_A ((4472832ull + 9437184ull) * 4ull)

// GAT1 fc1 + edge projections for ALL t, grid = T*B, block 256.
__global__ void gat1_fc(const float* __restrict__ inp, const float* __restrict__ W1,
                        const float* __restrict__ b1, const float* __restrict__ W2,
                        const float* __restrict__ b2,
                        float* __restrict__ x1_all, float* __restrict__ ps_all,
                        float* __restrict__ pr_all){
  int grp = blockIdx.x;
  int tid = threadIdx.x;
  __shared__ float sx1[N_*HID_];
  __shared__ float sW1[HID_*D_];
  __shared__ float sb1[HID_];
  __shared__ float sW2[HEAD_*2*HID_];
  __shared__ float sxin[N_*D_];
  if(tid < 64)  sW1[tid] = W1[tid];
  if(tid < 32)  sb1[tid] = b1[tid];
  sW2[tid] = W2[tid];
  if(tid < 128) sxin[tid] = inp[grp*N_*D_ + tid];
  __syncthreads();
  for(int o = tid; o < N_*HID_; o += 256){
    int n = o >> 5, k = o & 31;
    float v = sb1[k] + sxin[n*2]*sW1[k*2] + sxin[n*2+1]*sW1[k*2+1];
    sx1[o] = v;
    x1_all[grp*N_*HID_ + o] = v;
  }
  __syncthreads();
  for(int p = tid; p < N_*8; p += 256){
    int n = p >> 3, q = p & 7, hh = q & 3;
    const float* w  = sW2 + hh*64 + ((q < 4) ? 0 : 32);
    const float* xr = sx1 + n*32;
    float acc = (q < 4) ? b2[hh] : 0.f;
    #pragma unroll
    for(int c = 0; c < 32; c++) acc += xr[c]*w[c];
    if(q < 4) ps_all[grp*N_*HEAD_ + n*4 + hh] = acc;
    else      pr_all[grp*N_*HEAD_ + n*4 + hh] = acc;
  }
}

// Blocked-transposed GRU weights: WTb[k4][j][kk]; j<384 Wih, j>=384 Whh.
__global__ void prep_wt(const float* __restrict__ Wih, const float* __restrict__ Whh,
                        float* __restrict__ wtb){
  int idx = blockIdx.x*256 + threadIdx.x;
  int k4 = idx / 768, j = idx - k4*768;
  const float* src = (j < 384) ? (Wih + (size_t)j*H_) : (Whh + (size_t)(j-384)*H_);
  ((float4*)wtb)[idx] = ((const float4*)src)[k4];
}

// Big attention (all T). grid = 2*T*B (g, d-half), block 256.
__global__ __launch_bounds__(256) void gat_att_big2(const float* __restrict__ x1,
    const float* __restrict__ ps, const float* __restrict__ pr,
    float* __restrict__ out){
  int blk = blockIdx.x, g = blk >> 1, dh = blk & 1, tid = threadIdx.x;
  __shared__ float sX[N_*HID_];
  __shared__ float sPs[N_*HEAD_];
  __shared__ float sPr[N_*HEAD_];
  {
    const float4* xs = (const float4*)(x1 + (size_t)g*(N_*HID_));
    ((float4*)sX)[tid]       = xs[tid];
    ((float4*)sX)[tid + 256] = xs[tid + 256];
    sPs[tid] = ps[g*(N_*HEAD_) + tid];
    sPr[tid] = pr[g*(N_*HEAD_) + tid];
  }
  __syncthreads();
  float* outg = out + (size_t)g*(N_*H_);
  if(tid < NA_*HEAD_){
    int r = tid, hh = r & 3;
    float prv = sPr[r];
    float tmax = -1e30f;
    for(int i = 0; i < NA_; i++) tmax = fmaxf(tmax, sPs[i*4 + hh]);
    float m = eluf(tmax + prv);
    float4 acc[4];
    #pragma unroll
    for(int k = 0; k < 4; k++) acc[k] = make_float4(0.f,0.f,0.f,0.f);
    float s = 0.f;
    #pragma unroll 3
    for(int i = 0; i < NA_; i++){
      float tt = sPs[i*4 + hh] + prv;
      float v = tt > 0.f ? tt : expm1f(tt);
      float p = expf(v - m);
      s += p;
      const float4* sxp = (const float4*)&sX[i*32 + dh*16];
      #pragma unroll
      for(int k = 0; k < 4; k++){
        float4 xv = sxp[k];
        acc[k].x += p*xv.x; acc[k].y += p*xv.y;
        acc[k].z += p*xv.z; acc[k].w += p*xv.w;
      }
    }
    float inv = 1.f/s;
    float4* orow = (float4*)(outg + (r>>2)*H_ + hh*32 + dh*16);
    #pragma unroll
    for(int k = 0; k < 4; k++){
      float4 o;
      o.x = eluf(acc[k].x*inv); o.y = eluf(acc[k].y*inv);
      o.z = eluf(acc[k].z*inv); o.w = eluf(acc[k].w*inv);
      orow[k] = o;
    }
  } else {
    int hh = tid - NA_*HEAD_;
    float4 z4 = make_float4(0.f,0.f,0.f,0.f);
    float4* zp = (float4*)(outg + NA_*H_ + hh*32 + dh*16);
    zp[0]=z4; zp[1]=z4; zp[2]=z4; zp[3]=z4;
  }
}

// gi = xg @ Wih^T. Thread owns 3 gate-cols x 8 rows; block 256, grid 1536.
__global__ __launch_bounds__(256) void gi_gemm4(const float* __restrict__ xg,
    const float* __restrict__ wtb, float* __restrict__ gi){
  int tid = threadIdx.x;
  int r0 = blockIdx.x * 16;
  __shared__ __align__(16) float sxg[16][H_];
  ((float4*)sxg)[tid]       = ((const float4*)(xg + (size_t)r0*H_))[tid];
  ((float4*)sxg)[tid + 256] = ((const float4*)(xg + (size_t)r0*H_))[tid + 256];
  __syncthreads();
  int c = tid & 127, rh = (tid >> 7) * 8;
  const float4* wt4 = (const float4*)wtb;
  float ar[8]={0,0,0,0,0,0,0,0}, az[8]={0,0,0,0,0,0,0,0}, an[8]={0,0,0,0,0,0,0,0};
  #pragma unroll 2
  for(int k4 = 0; k4 < 32; k4++){
    float4 w0 = wt4[k4*768 + c];
    float4 w1 = wt4[k4*768 + 128 + c];
    float4 w2 = wt4[k4*768 + 256 + c];
    #pragma unroll
    for(int rr = 0; rr < 8; rr++){
      float4 xv = ((const float4*)sxg[rh + rr])[k4];
      ar[rr] += w0.x*xv.x + w0.y*xv.y + w0.z*xv.z + w0.w*xv.w;
      az[rr] += w1.x*xv.x + w1.y*xv.y + w1.z*xv.z + w1.w*xv.w;
      an[rr] += w2.x*xv.x + w2.y*xv.y + w2.z*xv.z + w2.w*xv.w;
    }
  }
  #pragma unroll
  for(int rr = 0; rr < 8; rr++){
    size_t base = (size_t)(r0 + rh + rr)*384;
    gi[base + c]       = ar[rr];
    gi[base + 128 + c] = az[rr];
    gi[base + 256 + c] = an[rr];
  }
}

// Fused loop kernel v4: 4 rows/block, grid 512, block 256 -> 2 blocks/CU so
// one block's barrier stalls hide under the other. Phases as gru_fc5:
// stage -> att(16 r x 16 lanes) -> GRU 2-way k-split -> combine -> fc1 -> fc2.
__global__ __launch_bounds__(256) void gru_fc8(
    const float* __restrict__ gi, const float* __restrict__ hidden0, int t0,
    const float* __restrict__ x2prev, const float* __restrict__ psprev,
    const float* __restrict__ prprev,
    const float* __restrict__ wtb,
    const float* __restrict__ bih, const float* __restrict__ bhh,
    const float* __restrict__ W1, const float* __restrict__ b1,
    const float* __restrict__ W2, const float* __restrict__ b2,
    float* __restrict__ x2, float* __restrict__ ps2, float* __restrict__ pr2){
  int tid = threadIdx.x, blk = blockIdx.x;
  int g0 = blk*4, g = blk>>4, jbase = (blk&15)*4;
  __shared__ __align__(16) float sX[N_*HID_];    // 8KB senders (att)
  __shared__ float sPs[N_*HEAD_];
  __shared__ __align__(16) float sh[4][H_];      // h rows (att out / GRU in)
  __shared__ __align__(16) float shn[4][H_];     // h_gru rows
  __shared__ float spart[2][12][H_];             // 12KB partial gate sums
  __shared__ float sx2[4][HID_];

  // ---- phase 0: stage ----
  if(t0){
    if(tid < 128) ((float4*)sh)[tid] = ((const float4*)(hidden0 + (size_t)g0*H_))[tid];
  } else {
    ((float4*)sX)[tid]       = ((const float4*)(x2prev + (size_t)g*(N_*HID_)))[tid];
    ((float4*)sX)[tid + 256] = ((const float4*)(x2prev + (size_t)g*(N_*HID_)))[tid + 256];
    sPs[tid] = psprev[g*(N_*HEAD_) + tid];
  }
  __syncthreads();

  // ---- phase 1: att for this block's 4 receiver rows (all 256 threads) ----
  if(!t0){
    int rl = tid >> 4, l16 = tid & 15;          // rl 0..15 = (jrow:4, hh:4)
    int hh = rl & 3, jrow = rl >> 2;
    int jl = jbase + jrow;
    float prv = prprev[g*(N_*HEAD_) + jbase*4 + rl];
    float tmax = -1e30f;
    for(int i = 0; i < NA_; i++) tmax = fmaxf(tmax, sPs[i*4 + hh]);
    float m = eluf(tmax + prv);
    float a0 = 0.f, a1 = 0.f, s = 0.f;
    #pragma unroll 3
    for(int i = 0; i < NA_; i++){
      float tt = sPs[i*4 + hh] + prv;
      float v = tt > 0.f ? tt : expm1f(tt);
      float p = expf(v - m);
      s += p;
      const float2 xv = *(const float2*)&sX[i*32 + l16*2];
      a0 += p*xv.x; a1 += p*xv.y;
    }
    float inv = 1.f/s;
    float h0 = (jl == NA_) ? 0.f : eluf(a0*inv);
    float h1 = (jl == NA_) ? 0.f : eluf(a1*inv);
    sh[jrow][hh*32 + l16*2]     = h0;
    sh[jrow][hh*32 + l16*2 + 1] = h1;
  }
  __syncthreads();

  // ---- phase 2: GRU partial dots (2-way k-split) ----
  int c = tid & 127, rg = tid >> 7;             // rg owns k4 = rg*16 .. rg*16+15
  {
    const float4* wt4 = (const float4*)wtb;
    float ar[4] = {0,0,0,0};
    float az[4] = {0,0,0,0};
    float an[4] = {0,0,0,0};
    #pragma unroll
    for(int kk = 0; kk < 16; kk++){
      int k4 = rg*16 + kk;
      const float4* wk = wt4 + (size_t)k4*768 + 384 + c;   // Whh half
      float4 wr_ = wk[0], wz_ = wk[128], wn_ = wk[256];
      #pragma unroll
      for(int r = 0; r < 4; r++){
        float4 hv = ((const float4*)sh[r])[k4];
        ar[r] += wr_.x*hv.x + wr_.y*hv.y + wr_.z*hv.z + wr_.w*hv.w;
        az[r] += wz_.x*hv.x + wz_.y*hv.y + wz_.z*hv.z + wz_.w*hv.w;
        an[r] += wn_.x*hv.x + wn_.y*hv.y + wn_.z*hv.z + wn_.w*hv.w;
      }
    }
    #pragma unroll
    for(int r = 0; r < 4; r++){
      spart[rg][r][c]     = ar[r];
      spart[rg][4 + r][c] = az[r];
      spart[rg][8 + r][c] = an[r];
    }
  }
  __syncthreads();

  // ---- phase 3: combine + GRU nonlinearity (2 rows/thread) ----
  {
    float bi_r = bih[c], bi_z = bih[c+H_], bi_n = bih[c+2*H_];
    float bh_r = bhh[c], bh_z = bhh[c+H_], bh_n = bhh[c+2*H_];
    int r0 = rg*2;
    #pragma unroll
    for(int rr = 0; rr < 2; rr++){
      int r = r0 + rr;
      float hr = spart[0][r][c]   + spart[1][r][c]   + bh_r;
      float hz = spart[0][4+r][c] + spart[1][4+r][c] + bh_z;
      float hn = spart[0][8+r][c] + spart[1][8+r][c] + bh_n;
      const float* gir = gi + (size_t)(g0+r)*384;
      float ir  = gir[c]     + bi_r;
      float iz  = gir[c+128] + bi_z;
      float in_ = gir[c+256] + bi_n;
      float rgt = 1.f/(1.f+expf(-(ir+hr)));
      float zgt = 1.f/(1.f+expf(-(iz+hz)));
      float ngt = tanhf(in_ + rgt*hn);
      shn[r][c] = (1.f-zgt)*ngt + zgt*sh[r][c];
    }
  }
  __syncthreads();

  // ---- phase 4: GAT2 fc1 (4 rows x 32 cols = 128 outputs) ----
  if(tid < 128){
    int r = tid >> 5, jc = tid & 31;
    const float4* wrow = (const float4*)(W1 + (size_t)jc*H_);
    const float4* hnr = (const float4*)shn[r];
    float acc = b1[jc];
    #pragma unroll 8
    for(int k4 = 0; k4 < 32; k4++){
      float4 w = wrow[k4], hv = hnr[k4];
      acc += w.x*hv.x + w.y*hv.y + w.z*hv.z + w.w*hv.w;
    }
    sx2[r][jc] = acc;
    x2[(size_t)(g0+r)*HID_ + jc] = acc;
  }
  __syncthreads();
  // ---- phase 5: GAT2 fc2 edge projections (4 rows x 8 q = 32 threads) ----
  if(tid < 32){
    int r = tid >> 3, q = tid & 7, hh = q & 3;
    int base = (q < 4) ? 0 : 32;
    float acc = (q < 4) ? b2[hh] : 0.f;
    #pragma unroll
    for(int cc = 0; cc < 32; cc++) acc += sx2[r][cc]*W2[hh*64 + base + cc];
    if(q < 4) ps2[(g0+r)*HEAD_ + hh] = acc;
    else      pr2[(g0+r)*HEAD_ + hh] = acc;
  }
}

// Fallback loop GRU (round-3 proven; used only if ws too small for gi).
__global__ __launch_bounds__(512) void gru_fc3(
    const float* __restrict__ xg, const float* __restrict__ h,
    const float* __restrict__ wtb,
    const float* __restrict__ bih, const float* __restrict__ bhh,
    const float* __restrict__ W1, const float* __restrict__ b1,
    const float* __restrict__ W2, const float* __restrict__ b2,
    float* __restrict__ x2, float* __restrict__ ps2, float* __restrict__ pr2){
  int tid = threadIdx.x;
  int g0 = blockIdx.x * 8;
  __shared__ __align__(16) float sx[8][H_];
  __shared__ __align__(16) float sh[8][H_];
  __shared__ __align__(16) float shn[8][H_];
  __shared__ float sx2[8][HID_];
  if(tid < 256) ((float4*)sx)[tid]     = ((const float4*)(xg + (size_t)g0*H_))[tid];
  else          ((float4*)sh)[tid-256] = ((const float4*)(h  + (size_t)g0*H_))[tid-256];
  __syncthreads();
  int c = tid & 127, rg = tid >> 7, r0 = rg*2;
  const float4* wt4 = (const float4*)wtb;
  const float4* xr0 = (const float4*)sx[r0];
  const float4* xr1 = (const float4*)sx[r0+1];
  const float4* hp0 = (const float4*)sh[r0];
  const float4* hp1 = (const float4*)sh[r0+1];
  float air[2]={0,0}, aiz[2]={0,0}, ain[2]={0,0};
  float ahr[2]={0,0}, ahz[2]={0,0}, ahn[2]={0,0};
  #pragma unroll 2
  for(int k4 = 0; k4 < 32; k4++){
    const float4* wk = wt4 + k4*768 + c;
    float4 w0 = wk[0],   w1 = wk[128], w2 = wk[256];
    float4 w3 = wk[384], w4 = wk[512], w5 = wk[640];
    float4 xv0 = xr0[k4], xv1 = xr1[k4];
    float4 hv0 = hp0[k4], hv1 = hp1[k4];
    air[0] += w0.x*xv0.x + w0.y*xv0.y + w0.z*xv0.z + w0.w*xv0.w;
    aiz[0] += w1.x*xv0.x + w1.y*xv0.y + w1.z*xv0.z + w1.w*xv0.w;
    ain[0] += w2.x*xv0.x + w2.y*xv0.y + w2.z*xv0.z + w2.w*xv0.w;
    ahr[0] += w3.x*hv0.x + w3.y*hv0.y + w3.z*hv0.z + w3.w*hv0.w;
    ahz[0] += w4.x*hv0.x + w4.y*hv0.y + w4.z*hv0.z + w4.w*hv0.w;
    ahn[0] += w5.x*hv0.x + w5.y*hv0.y + w5.z*hv0.z + w5.w*hv0.w;
    air[1] += w0.x*xv1.x + w0.y*xv1.y + w0.z*xv1.z + w0.w*xv1.w;
    aiz[1] += w1.x*xv1.x + w1.y*xv1.y + w1.z*xv1.z + w1.w*xv1.w;
    ain[1] += w2.x*xv1.x + w2.y*xv1.y + w2.z*xv1.z + w2.w*xv1.w;
    ahr[1] += w3.x*hv1.x + w3.y*hv1.y + w3.z*hv1.z + w3.w*hv1.w;
    ahz[1] += w4.x*hv1.x + w4.y*hv1.y + w4.z*hv1.z + w4.w*hv1.w;
    ahn[1] += w5.x*hv1.x + w5.y*hv1.y + w5.z*hv1.z + w5.w*hv1.w;
  }
  float bi_r = bih[c], bi_z = bih[c+H_], bi_n = bih[c+2*H_];
  float bh_r = bhh[c], bh_z = bhh[c+H_], bh_n = bhh[c+2*H_];
  #pragma unroll
  for(int rr = 0; rr < 2; rr++){
    float ir  = air[rr]+bi_r, iz = aiz[rr]+bi_z, in_ = ain[rr]+bi_n;
    float hr  = ahr[rr]+bh_r, hz = ahz[rr]+bh_z, hn  = ahn[rr]+bh_n;
    float rgt = 1.f/(1.f+expf(-(ir+hr)));
    float zgt = 1.f/(1.f+expf(-(iz+hz)));
    float ngt = tanhf(in_ + rgt*hn);
    shn[r0+rr][c] = (1.f-zgt)*ngt + zgt*sh[r0+rr][c];
  }
  __syncthreads();
  if(tid < 256){
    int r = tid >> 5, jc = tid & 31;
    const float4* wrow = (const float4*)(W1 + (size_t)jc*H_);
    const float4* hnr = (const float4*)shn[r];
    float acc = b1[jc];
    #pragma unroll 8
    for(int k4 = 0; k4 < 32; k4++){
      float4 w = wrow[k4], hv = hnr[k4];
      acc += w.x*hv.x + w.y*hv.y + w.z*hv.z + w.w*hv.w;
    }
    sx2[r][jc] = acc;
    x2[(size_t)(g0+r)*HID_ + jc] = acc;
  }
  __syncthreads();
  if(tid < 64){
    int r = tid >> 3, q = tid & 7, hh = q & 3;
    int base = (q < 4) ? 0 : 32;
    float acc = (q < 4) ? b2[hh] : 0.f;
    #pragma unroll
    for(int cc = 0; cc < 32; cc++) acc += sx2[r][cc]*W2[hh*64 + base + cc];
    if(q < 4) ps2[(g0+r)*HEAD_ + hh] = acc;
    else      pr2[(g0+r)*HEAD_ + hh] = acc;
  }
}

// Loop/final attention. grid = B*8, block 128. (rh = r-half, dq = d-quarter).
__global__ __launch_bounds__(128) void gat_att_sm(const float* __restrict__ x1,
    const float* __restrict__ ps, const float* __restrict__ pr,
    float* __restrict__ out){
  int bid = blockIdx.x;
  int g = bid >> 3, sub = bid & 7, rh = sub >> 2, dq = sub & 3;
  int tid = threadIdx.x;
  __shared__ float sX[N_*HID_];
  __shared__ float sPs[N_*HEAD_];
  __shared__ float sPr[N_*HEAD_];
  {
    const float4* xs = (const float4*)(x1 + (size_t)g*(N_*HID_));
    #pragma unroll
    for(int k = 0; k < 4; k++) ((float4*)sX)[tid + 128*k] = xs[tid + 128*k];
    sPs[tid]       = ps[g*(N_*HEAD_) + tid];
    sPs[tid + 128] = ps[g*(N_*HEAD_) + tid + 128];
    sPr[tid]       = pr[g*(N_*HEAD_) + tid];
    sPr[tid + 128] = pr[g*(N_*HEAD_) + tid + 128];
  }
  __syncthreads();
  float* outg = out + (size_t)g*(N_*H_);
  if(tid < 126){
    int r = rh*126 + tid;
    int hh = r & 3, j = r >> 2;
    float prv = sPr[r];
    float tmax = -1e30f;
    for(int i = 0; i < NA_; i++) tmax = fmaxf(tmax, sPs[i*4 + hh]);
    float m = eluf(tmax + prv);
    float4 a0 = make_float4(0.f,0.f,0.f,0.f), a1 = a0;
    float s = 0.f;
    #pragma unroll 3
    for(int i = 0; i < NA_; i++){
      float tt = sPs[i*4 + hh] + prv;
      float v = tt > 0.f ? tt : expm1f(tt);
      float p = expf(v - m);
      s += p;
      const float4* sxp = (const float4*)&sX[i*32 + dq*8];
      float4 x0 = sxp[0], x1v = sxp[1];
      a0.x += p*x0.x;  a0.y += p*x0.y;  a0.z += p*x0.z;  a0.w += p*x0.w;
      a1.x += p*x1v.x; a1.y += p*x1v.y; a1.z += p*x1v.z; a1.w += p*x1v.w;
    }
    float inv = 1.f/s;
    float4* orow = (float4*)(outg + (size_t)j*H_ + hh*32 + dq*8);
    float4 o0, o1;
    o0.x = eluf(a0.x*inv); o0.y = eluf(a0.y*inv);
    o0.z = eluf(a0.z*inv); o0.w = eluf(a0.w*inv);
    o1.x = eluf(a1.x*inv); o1.y = eluf(a1.y*inv);
    o1.z = eluf(a1.z*inv); o1.w = eluf(a1.w*inv);
    orow[0] = o0; orow[1] = o1;
  } else if(rh == 1){
    float4 z4 = make_float4(0.f,0.f,0.f,0.f);
    float4* zrow = (float4*)(outg + NA_*H_);
    int base = dq*8 + (tid-126)*4;
    #pragma unroll
    for(int k = 0; k < 4; k++) zrow[base + k] = z4;
  }
}

// pred = h @ out_W.T + out_b. grid B, block 128.
__global__ void final_k(const float* __restrict__ h, const float* __restrict__ oW,
                        const float* __restrict__ ob, float* __restrict__ out){
  int b = blockIdx.x, tid = threadIdx.x;
  int n = tid >> 1, d = tid & 1;
  const float* hr = h + (size_t)(b*N_ + n)*H_;
  float acc = ob[d];
  #pragma unroll 8
  for(int k = 0; k < H_; k++) acc += hr[k]*oW[d*H_ + k];
  out[(b*N_ + n)*D_ + d] = acc;
}

extern "C" void kernel_launch(void* const* d_in, const int* in_sizes, int n_in,
                              void* d_out, int out_size, void* d_ws, size_t ws_size,
                              hipStream_t stream){
  const float* inputs = (const float*)d_in[0];
  const float* hidden = (const float*)d_in[1];
  const float* rn1_W1 = (const float*)d_in[4];
  const float* rn1_b1 = (const float*)d_in[5];
  const float* rn1_W2 = (const float*)d_in[6];
  const float* rn1_b2 = (const float*)d_in[7];
  const float* rn2_W1 = (const float*)d_in[8];
  const float* rn2_b1 = (const float*)d_in[9];
  const float* rn2_W2 = (const float*)d_in[10];
  const float* rn2_b2 = (const float*)d_in[11];
  const float* gWih   = (const float*)d_in[12];
  const float* gWhh   = (const float*)d_in[13];
  const float* gbih   = (const float*)d_in[14];
  const float* gbhh   = (const float*)d_in[15];
  const float* oW     = (const float*)d_in[16];
  const float* ob     = (const float*)d_in[17];
  float* ws = (float*)d_ws;

  const int use_gi = (ws_size >= WS_NEED_A) ? 1 : 0;

  gat1_fc<<<T_*B_, 256, 0, stream>>>(inputs, rn1_W1, rn1_b1, rn1_W2, rn1_b2,
                                     ws + OFF_X1, ws + OFF_PS1, ws + OFF_PR1);
  gat_att_big2<<<T_*B_*2, 256, 0, stream>>>(ws + OFF_X1, ws + OFF_PS1, ws + OFF_PR1,
                                            ws + OFF_XG);
  prep_wt<<<96, 256, 0, stream>>>(gWih, gWhh, ws + OFF_WT);

  const float* xg0  = ws + OFF_XG;
  const float* wtbp = ws + OFF_WT;
  float* hb  = ws + OFF_H;

  if(use_gi){
    gi_gemm4<<<T_*B_*N_/16, 256, 0, stream>>>(xg0, wtbp, ws + OFF_GI);
    // double-buffered x2/ps/pr (odd set reuses dead PS1/PR1 regions)
    float* x2b[2] = {ws + OFF_X2,  ws + OFF_PS1};
    float* psb[2] = {ws + OFF_PS2, ws + OFF_PR1};
    float* prb[2] = {ws + OFF_PR2, ws + OFF_PR1 + 8192};
    for(int t = 0; t < T_; t++){
      int w = t & 1, rp = w ^ 1;
      gru_fc8<<<B_*N_/4, 256, 0, stream>>>(ws + OFF_GI + (size_t)t*B_*N_*384,
                                           hidden, (t == 0) ? 1 : 0,
                                           x2b[rp], psb[rp], prb[rp],
                                           wtbp, gbih, gbhh,
                                           rn2_W1, rn2_b1, rn2_W2, rn2_b2,
                                           x2b[w], psb[w], prb[w]);
    }
    // T_-1 = 11 is odd -> final buffers are set 1
    gat_att_sm<<<B_*8, 128, 0, stream>>>(x2b[1], psb[1], prb[1], hb);
  } else {
    float* x2p = ws + OFF_X2;
    float* psp = ws + OFF_PS2;
    float* prp = ws + OFF_PR2;
    for(int t = 0; t < T_; t++){
      const float* hsrc = (t == 0) ? hidden : hb;
      gru_fc3<<<B_*N_/8, 512, 0, stream>>>(xg0 + (size_t)t*B_*N_*H_, hsrc,
                                           wtbp, gbih, gbhh,
                                           rn2_W1, rn2_b1, rn2_W2, rn2_b2,
                                           x2p, psp, prp);
      gat_att_sm<<<B_*8, 128, 0, stream>>>(x2p, psp, prp, hb);
    }
  }
  // UNCONDITIONAL (rounds 9-12 had this inside the else-branch — the bug).
  final_k<<<B_, 128, 0, stream>>>(hb, oW, ob, (float*)d_out);
}